// Round 1
// baseline (232.333 us; speedup 1.0000x reference)
//
#include <hip/hip_runtime.h>

typedef unsigned long long u64;

// Problem constants (match reference setup_inputs)
#define NSETS 8
#define NPTS  4096
#define DF    16
#define KNN   16
#define QPB   64                  // queries per block (one per lane)
#define NCH   8                   // waves per block
#define BLK   (QPB * NCH)         // 512 threads
#define TILE  512                 // candidates staged into LDS per tile
#define NTILE (NPTS / TILE)       // 8
#define SLICE (TILE / NCH)        // 64 candidates per wave per tile
#define NEDGE (NSETS * NPTS * KNN)

// Round-8: r7 counters: VALUBusy 84%, HBM 0.9%, occupancy 36% -> pure
// VALU-issue-bound. Issue arithmetic: ~50k VALU instr/lane, scan floor is
// ~13k -> ~75% of issue is top-k maintenance. Cause: the 16-deep
// shift-insert (~100 VALU) runs WAVE-WIDE whenever __any of 64 lanes
// inserts (P~1 through the whole scan). Fix: divergence-free batch flush on
// packed u64 (orderable_dist_bits<<32 | idx) keys: odd-even sort-8 +
// keep-16 min-pair + bitonic merge-16 = ~290 VALU per 8-entry flush,
// deterministic, exact (dist,idx)-lex semantics (bit-identical output).
// Also: merge overlay stride 16->17 floats kills the 32-way bank conflict
// (2.07M conflicts -> ~0).
#define RES      8                // reservoir slots/lane (max cnt = 4+GRP = 8)
#define FLUSH_AT 5                // flush when any lane cnt >= this
#define GRP      4                // candidates between flush checks

#define FEAT_B   (TILE * DF * 4)            // 32768 B: feat4[4][TILE] transposed
#define NRM_B    (TILE * 4)                 // 2048 B:  nrm_t[TILE]
#define RESV_OFF (FEAT_B + NRM_B)           // 34816
#define SMEM_B   (RESV_OFF + RES * BLK * 8) // 67584 B -> 2 blocks/CU
#define MPAD     17                         // merge-overlay stride (17 coprime 32)

// positive/negative-safe orderable-uint mapping for f32 (handles the ~±0
// diagonal self-distance)
__device__ __forceinline__ unsigned flip_f(float d) {
    unsigned b = __float_as_uint(d);
    return (b & 0x80000000u) ? ~b : (b | 0x80000000u);
}
__device__ __forceinline__ float unflip_f(unsigned u) {
    unsigned b = (u & 0x80000000u) ? (u ^ 0x80000000u) : ~u;
    return __uint_as_float(b);
}

// compare-exchange: ascending (min at i), u64 key carries (dist, idx)
#define CEB(i, j) { u64 _a = B[i], _b = B[j]; bool _c = _b < _a; \
                    B[i] = _c ? _b : _a; B[j] = _c ? _a : _b; }
#define CEL(i, j) { u64 _a = Lk[i], _b = Lk[j]; bool _c = _b < _a; \
                    Lk[i] = _c ? _b : _a; Lk[j] = _c ? _a : _b; }

__global__ __launch_bounds__(BLK) void knn_kernel(const float* __restrict__ x,
                                                  float* __restrict__ out) {
    __shared__ float tau_sh[QPB];                 // shared per-query tau
    __shared__ __align__(16) char smem[SMEM_B];
    float4* feat4 = (float4*)smem;                // feat4[r*TILE + c], r=0..3
    float*  nrm_t = (float*)(smem + FEAT_B);      // candidate norms
    u64*    resv  = (u64*)(smem + RESV_OFF);      // resv[slot*BLK + t], u64 keys
    float*          lds_d = (float*)smem;                     // overlay (post-scan)
    unsigned short* lds_i = (unsigned short*)(smem + BLK * MPAD * 4);

    const int t    = threadIdx.x;
    const int lane = t & 63;
    const int wv   = t >> 6;                    // slice index 0..7
    const int set  = blockIdx.x >> 6;           // 64 blocks per set
    const int q0   = (blockIdx.x & 63) * QPB;
    const int q    = q0 + lane;                 // this lane's query point

    const float* xs = x + (size_t)set * NPTS * DF;

    if (t < QPB) tau_sh[t] = 3.0e38f;

    // Query features; q2 via the SAME pairwise tree as candidate norms (bit-
    // identical to r3's Phase A formula). qn = -2*q: exact pow2 scaling
    // commutes with fma rounding -> dist bit-identical to prior rounds.
    float qn[DF];
    float q2;
    {
        const float4* qp = (const float4*)(xs + (size_t)q * DF);
        float4 a = qp[0], b = qp[1], g = qp[2], d = qp[3];
        float r0 = __fadd_rn(__fmul_rn(a.x, a.x), __fmul_rn(g.x, g.x));
        float r1 = __fadd_rn(__fmul_rn(a.y, a.y), __fmul_rn(g.y, g.y));
        float r2 = __fadd_rn(__fmul_rn(a.z, a.z), __fmul_rn(g.z, g.z));
        float r3 = __fadd_rn(__fmul_rn(a.w, a.w), __fmul_rn(g.w, g.w));
        float r4 = __fadd_rn(__fmul_rn(b.x, b.x), __fmul_rn(d.x, d.x));
        float r5 = __fadd_rn(__fmul_rn(b.y, b.y), __fmul_rn(d.y, d.y));
        float r6 = __fadd_rn(__fmul_rn(b.z, b.z), __fmul_rn(d.z, d.z));
        float r7 = __fadd_rn(__fmul_rn(b.w, b.w), __fmul_rn(d.w, d.w));
        q2 = __fadd_rn(__fadd_rn(__fadd_rn(r0, r1), __fadd_rn(r2, r3)),
                       __fadd_rn(__fadd_rn(r4, r5), __fadd_rn(r6, r7)));
        qn[0]=a.x; qn[1]=a.y; qn[2]=a.z; qn[3]=a.w;
        qn[4]=b.x; qn[5]=b.y; qn[6]=b.z; qn[7]=b.w;
        qn[8]=g.x; qn[9]=g.y; qn[10]=g.z; qn[11]=g.w;
        qn[12]=d.x; qn[13]=d.y; qn[14]=d.z; qn[15]=d.w;
#pragma unroll
        for (int d2 = 0; d2 < DF; ++d2) qn[d2] = -2.0f * qn[d2];
    }

    // Sorted (ascending) top-16 as packed u64 keys. Sentinel unflips to 3e38.
    const u64 SENT = ((u64)flip_f(3.0e38f) << 32) | 0xFFFFFFFFull;
    u64   Lk[KNN];
#pragma unroll
    for (int j = 0; j < KNN; ++j) Lk[j] = SENT;
    float tau_reg = 3.0e38f;     // == unflip(Lk[15]) at all flush boundaries
    int   cnt = 0;

    // Divergence-free batch drain: sort the 8-slot reservoir (sentinel-padded
    // per lane), min-pair into the tail of Lk (provably keeps the 16 smallest
    // and leaves Lk bitonic), bitonic-merge-16 back to sorted. Key order is
    // exact (dist, idx) lexicographic == reference stable-top-k order.
    auto flush = [&]() {
        u64 B[RES];
#pragma unroll
        for (int e = 0; e < RES; ++e) {
            u64 v = resv[e * BLK + t];
            B[e] = (e < cnt) ? v : SENT;
        }
        // Batcher odd-even mergesort, 8 keys, 19 CEs
        CEB(0,1) CEB(2,3) CEB(4,5) CEB(6,7)
        CEB(0,2) CEB(1,3) CEB(4,6) CEB(5,7)
        CEB(1,2) CEB(5,6)
        CEB(0,4) CEB(1,5) CEB(2,6) CEB(3,7)
        CEB(2,4) CEB(3,5)
        CEB(1,2) CEB(3,4) CEB(5,6)
        // keep-16: L[15-i] = min(L[15-i], B[i]) -> L becomes bitonic
#pragma unroll
        for (int i = 0; i < RES; ++i) {
            u64 a = Lk[KNN - 1 - i], b = B[i];
            Lk[KNN - 1 - i] = (b < a) ? b : a;
        }
        // bitonic merge 16 -> ascending
        CEL(0,8)  CEL(1,9)  CEL(2,10) CEL(3,11)
        CEL(4,12) CEL(5,13) CEL(6,14) CEL(7,15)
        CEL(0,4)  CEL(1,5)  CEL(2,6)  CEL(3,7)
        CEL(8,12) CEL(9,13) CEL(10,14) CEL(11,15)
        CEL(0,2)  CEL(1,3)  CEL(4,6)  CEL(5,7)
        CEL(8,10) CEL(9,11) CEL(12,14) CEL(13,15)
        CEL(0,1)  CEL(2,3)  CEL(4,5)  CEL(6,7)
        CEL(8,9)  CEL(10,11) CEL(12,13) CEL(14,15)
        cnt = 0;
        const float kth = unflip_f((unsigned)(Lk[KNN - 1] >> 32));
        tau_reg = kth;
        volatile float* ts = (volatile float*)tau_sh;   // benign-race cons. min
        float cur = ts[lane];
        ts[lane] = fminf(cur, kth);
    };

    for (int tile = 0; tile < NTILE; ++tile) {
        __syncthreads();   // previous tile fully consumed (also covers tau init)
        {
            // Thread t stages candidate tile*TILE+t: features (transposed
            // float4 rows) + norm via the exact Phase-A tree, in registers.
            const int c = tile * TILE + t;
            const float4* p = (const float4*)(xs + (size_t)c * DF);
            float4 a = p[0], b = p[1], g = p[2], d = p[3];
            float r0 = __fadd_rn(__fmul_rn(a.x, a.x), __fmul_rn(g.x, g.x));
            float r1 = __fadd_rn(__fmul_rn(a.y, a.y), __fmul_rn(g.y, g.y));
            float r2 = __fadd_rn(__fmul_rn(a.z, a.z), __fmul_rn(g.z, g.z));
            float r3 = __fadd_rn(__fmul_rn(a.w, a.w), __fmul_rn(g.w, g.w));
            float r4 = __fadd_rn(__fmul_rn(b.x, b.x), __fmul_rn(d.x, d.x));
            float r5 = __fadd_rn(__fmul_rn(b.y, b.y), __fmul_rn(d.y, d.y));
            float r6 = __fadd_rn(__fmul_rn(b.z, b.z), __fmul_rn(d.z, d.z));
            float r7 = __fadd_rn(__fmul_rn(b.w, b.w), __fmul_rn(d.w, d.w));
            feat4[0 * TILE + t] = a;
            feat4[1 * TILE + t] = b;
            feat4[2 * TILE + t] = g;
            feat4[3 * TILE + t] = d;
            nrm_t[t] = __fadd_rn(
                __fadd_rn(__fadd_rn(r0, r1), __fadd_rn(r2, r3)),
                __fadd_rn(__fadd_rn(r4, r5), __fadd_rn(r6, r7)));
        }
        __syncthreads();

        const int lbase = wv * SLICE;            // local slice base in tile
        const int gbase = tile * TILE + lbase;   // global candidate id base

        for (int g = 0; g < SLICE; g += GRP) {
            const float tsh = ((volatile float*)tau_sh)[lane];
            const float tau = fminf(tsh, tau_reg);
#pragma unroll
            for (int u = 0; u < GRP; ++u) {
                const int lc = lbase + g + u;    // wave-uniform -> broadcast
                float4 f0 = feat4[0 * TILE + lc];
                float4 f1 = feat4[1 * TILE + lc];
                float4 f2 = feat4[2 * TILE + lc];
                float4 f3 = feat4[3 * TILE + lc];
                const float nc = nrm_t[lc];
                float dot = 0.f;
                dot = fmaf(qn[0],  f0.x, dot); dot = fmaf(qn[1],  f0.y, dot);
                dot = fmaf(qn[2],  f0.z, dot); dot = fmaf(qn[3],  f0.w, dot);
                dot = fmaf(qn[4],  f1.x, dot); dot = fmaf(qn[5],  f1.y, dot);
                dot = fmaf(qn[6],  f1.z, dot); dot = fmaf(qn[7],  f1.w, dot);
                dot = fmaf(qn[8],  f2.x, dot); dot = fmaf(qn[9],  f2.y, dot);
                dot = fmaf(qn[10], f2.z, dot); dot = fmaf(qn[11], f2.w, dot);
                dot = fmaf(qn[12], f3.x, dot); dot = fmaf(qn[13], f3.y, dot);
                dot = fmaf(qn[14], f3.z, dot); dot = fmaf(qn[15], f3.w, dot);
                const float dist = __fadd_rn(__fadd_rn(q2, nc), dot);
                if (dist <= tau) {               // non-strict: keep boundary ties
                    resv[cnt * BLK + t] =
                        ((u64)flip_f(dist) << 32) | (unsigned)(gbase + g + u);
                    ++cnt;
                }
            }
            if (__any(cnt >= FLUSH_AT)) flush();
        }
    }
    flush();                                      // final drain

    // ---- Merge the 8 per-slice lists and emit ------------------------------
    __syncthreads();   // overlay aliases tile + other threads' reservoir slots
#pragma unroll
    for (int j = 0; j < KNN; ++j) {
        lds_d[t * MPAD + j] = unflip_f((unsigned)(Lk[j] >> 32));
        lds_i[t * MPAD + j] = (unsigned short)(Lk[j] & 0xFFFFu);
    }
    __syncthreads();

    if (t < QPB) {
        const int l = t;
        float h[NCH];
        int   hi[NCH];
        int   p[NCH];
#pragma unroll
        for (int w2 = 0; w2 < NCH; ++w2) {
            p[w2]  = 0;
            h[w2]  = lds_d[(w2 * QPB + l) * MPAD];
            hi[w2] = (int)lds_i[(w2 * QPB + l) * MPAD];
        }

        const int    gq = set * NPTS + q0 + l;
        const size_t eb = (size_t)gq * KNN;
        float* osrc = out;
        float* odst = out + (size_t)NEDGE;
        float* odis = out + 2 * (size_t)NEDGE;
        const float srcf = (float)gq;

        for (int e = 0; e < KNN; ++e) {
            // (dist, idx) lexicographic min across the 8 heads — exact stable
            // top-k order (slices are strided, so idx must break ties).
            float best = h[0];
            int   bi   = hi[0];
            int   bw   = 0;
#pragma unroll
            for (int w2 = 1; w2 < NCH; ++w2) {
                const bool better = (h[w2] < best) ||
                                    (h[w2] == best && hi[w2] < bi);
                if (better) { best = h[w2]; bi = hi[w2]; bw = w2; }
            }

#pragma unroll
            for (int w2 = 0; w2 < NCH; ++w2) {
                if (bw == w2) {
                    ++p[w2];
                    if (p[w2] < KNN) {
                        h[w2]  = lds_d[(w2 * QPB + l) * MPAD + p[w2]];
                        hi[w2] = (int)lds_i[(w2 * QPB + l) * MPAD + p[w2]];
                    } else {
                        h[w2]  = 3.0e38f;
                        hi[w2] = 0x7FFFFFFF;
                    }
                }
            }

            osrc[eb + e] = srcf;
            odst[eb + e] = (float)(set * NPTS + bi);
            odis[eb + e] = best;
        }
    }
}

// ---------------------------------------------------------------------------
extern "C" void kernel_launch(void* const* d_in, const int* in_sizes, int n_in,
                              void* d_out, int out_size, void* d_ws, size_t ws_size,
                              hipStream_t stream) {
    (void)in_sizes; (void)n_in; (void)out_size; (void)d_ws; (void)ws_size;
    const float* x = (const float*)d_in[0];  // (8, 4096, 16) f32
    float* out = (float*)d_out;              // [src|dst|dist] f32

    knn_kernel<<<NSETS * (NPTS / QPB), BLK, 0, stream>>>(x, out);
}